// Round 9
// baseline (320.854 us; speedup 1.0000x reference)
//
#include <hip/hip_runtime.h>
#include <math.h>

#define LDIM 256
#define NCODES 1024
#define HID 256
#define NLAY 5
#define NVQ 4
#define CC_ 0.25f
#define OMEGA_ 30.0f
#define BATCH 16
#define NPTS 4096
#define PTILE 128

// ws layout (bytes):
//   [0      .. 16383 ] z per batch (16x256 f32)
//   [16384  .. 16895 ] winners: 16 batches x 4 stages u64, packed (mono_dist<<32)|idx
//   [32768  .. 163839] FiLM params (film_kernel -> siren)
//   fast path only (requires ws_size >= 1,245,184):
//   [196608 .. 720895] wp_hi: bf16 hi plane, short[4][256 h][256 k]
//   [720896 .. 1245183] wp_lo: bf16 lo plane
#define WIN_OFF 4096      // float index of winners
#define FILM_OFF 8192     // float index of film params
#define WP_BYTE 196608
#define FAST_WS_NEEDED 1245184u

typedef __attribute__((ext_vector_type(8))) short short8;
typedef __attribute__((ext_vector_type(4))) float f32x4;

// truncation hi/lo split: x ~= hi + lo, |err| <~ 2^-17 |x|
__device__ __forceinline__ unsigned int pack_split(float x) {
  unsigned int u = __builtin_bit_cast(unsigned int, x);
  float hf = __builtin_bit_cast(float, u & 0xffff0000u);
  float lf = x - hf;
  unsigned int ul = __builtin_bit_cast(unsigned int, lf);
  return (u & 0xffff0000u) | (ul >> 16);
}
__device__ __forceinline__ void split_trunc(float x, short& hi, short& lo) {
  unsigned int u = __builtin_bit_cast(unsigned int, x);
  float hf = __builtin_bit_cast(float, u & 0xffff0000u);
  float lf = x - hf;
  hi = (short)(u >> 16);
  lo = (short)(__builtin_bit_cast(unsigned int, lf) >> 16);
}
__device__ __forceinline__ float bf16_hi_f(unsigned short h) {
  return __builtin_bit_cast(float, (unsigned int)h << 16);
}
// order-preserving float->uint map (total order incl. negatives)
__device__ __forceinline__ unsigned int mono_u32(float f) {
  unsigned int u = __builtin_bit_cast(unsigned int, f);
  return (u & 0x80000000u) ? ~u : (u | 0x80000000u);
}

// ---------------- VQ init: z = sum_v latents; winners := +inf ----------------
__global__ __launch_bounds__(256) void vq_init(const int* __restrict__ lidx,
                                               const float* __restrict__ latents,
                                               float* __restrict__ ws) {
  const int t = threadIdx.x, b = blockIdx.x;
  const int ib = lidx[b];
  float z = 0.f;
  #pragma unroll
  for (int v = 0; v < NVQ; ++v) z += latents[((size_t)ib * NVQ + v) * LDIM + t];
  ws[b * LDIM + t] = z;
  if (t < NVQ) ((unsigned long long*)(ws + WIN_OFF))[b * NVQ + t] = ~0ULL;
}

// ---------------- VQ stage: recompute residual, partial argmin, atomic merge ----------------
__global__ __launch_bounds__(256) void vq_stage(const float* __restrict__ emb,
                                                float* __restrict__ ws, int stage) {
  __shared__ __align__(16) float Ech[32 * 260];
  __shared__ __align__(16) float r_s[LDIM];
  __shared__ float mval[256];
  __shared__ int   midx[256];
  const int t = threadIdx.x;
  const int b = blockIdx.x >> 3;
  const int slice = blockIdx.x & 7;
  const unsigned long long* wsl = (const unsigned long long*)(ws + WIN_OFF);
  float r = ws[b * LDIM + t];
  for (int j = 0; j < stage; ++j) {
    int wj = (int)(wsl[b * NVQ + j] & 0xffffffffULL);
    r -= emb[((size_t)j * NCODES + wj) * LDIM + t];
  }
  r_s[t] = r;
  __syncthreads();
  const float* E = emb + (size_t)stage * NCODES * LDIM + (size_t)slice * 128 * LDIM;
  const float4* E4 = (const float4*)E;
  const int cg = t >> 3;
  const int dq = t & 7;
  float bestv = 3.4e38f; int besti = 0;
  for (int ch = 0; ch < 4; ++ch) {
    __syncthreads();
    #pragma unroll
    for (int it = 0; it < 8; ++it) {
      int f = it * 256 + t;
      int row = f >> 6;
      int col4 = f & 63;
      *(float4*)&Ech[row * 260 + col4 * 4] = E4[(size_t)(ch * 32 + row) * 64 + col4];
    }
    __syncthreads();
    float dot = 0.f, e2 = 0.f;
    const float* er = &Ech[cg * 260];
    const float4* rr4 = (const float4*)r_s;
    #pragma unroll
    for (int j = 0; j < 8; ++j) {
      int d4 = dq + 8 * j;
      float4 e = *(const float4*)&er[d4 * 4];
      float4 rv = rr4[d4];
      dot += e.x * rv.x + e.y * rv.y + e.z * rv.z + e.w * rv.w;
      e2  += e.x * e.x + e.y * e.y + e.z * e.z + e.w * e.w;
    }
    dot += __shfl_xor(dot, 1); e2 += __shfl_xor(e2, 1);
    dot += __shfl_xor(dot, 2); e2 += __shfl_xor(e2, 2);
    dot += __shfl_xor(dot, 4); e2 += __shfl_xor(e2, 4);
    if (dq == 0) {
      float dist = e2 - 2.f * dot;   // +||r||^2 constant: argmin-invariant
      int c = slice * 128 + ch * 32 + cg;
      if (dist < bestv) { bestv = dist; besti = c; }
    }
  }
  mval[t] = (dq == 0) ? bestv : 3.4e38f;
  midx[t] = (dq == 0) ? besti : (1 << 30);
  __syncthreads();
  for (int off = 128; off > 0; off >>= 1) {
    if (t < off) {
      float ov = mval[t + off]; int oi = midx[t + off];
      if (ov < mval[t] || (ov == mval[t] && oi < midx[t])) { mval[t] = ov; midx[t] = oi; }
    }
    __syncthreads();
  }
  if (t == 0) {
    unsigned long long pack =
        ((unsigned long long)mono_u32(mval[0]) << 32) | (unsigned int)midx[0];
    atomicMin((unsigned long long*)(ws + WIN_OFF) + (b * NVQ + stage), pack);
  }
}

// ---------------- VQ loss (1 block) ----------------
__global__ __launch_bounds__(256) void vq_loss(const float* __restrict__ emb,
                                               const float* __restrict__ ws,
                                               float* __restrict__ loss_out) {
  __shared__ float red[256];
  const int t = threadIdx.x;
  const unsigned long long* wsl = (const unsigned long long*)(ws + WIN_OFF);
  float acc = 0.f;
  for (int b = 0; b < BATCH; ++b) {
    float r = ws[b * LDIM + t];
    #pragma unroll
    for (int s = 0; s < NVQ; ++s) {
      int w = (int)(wsl[b * NVQ + s] & 0xffffffffULL);
      float e = emb[((size_t)s * NCODES + w) * LDIM + t];
      float d = e - r;
      acc += d * d;
      r -= e;
    }
  }
  red[t] = acc;
  __syncthreads();
  for (int off = 128; off > 0; off >>= 1) {
    if (t < off) red[t] += red[t + off];
    __syncthreads();
  }
  if (t == 0) loss_out[0] = red[0] * (CC_ / (NVQ * BATCH * LDIM));
}

// ---------------- FiLM params (layers 1..4) ----------------
__global__ __launch_bounds__(256) void film_kernel(const float* __restrict__ emb,
                                                   const float* __restrict__ mod_W,
                                                   const float* __restrict__ mod_b,
                                                   float* __restrict__ ws) {
  __shared__ float z_s[LDIM];
  const int t = threadIdx.x;
  const int li = blockIdx.x & 3;
  const int b  = blockIdx.x >> 2;
  const int l  = li + 1;
  const unsigned long long* wsl = (const unsigned long long*)(ws + WIN_OFF);
  float z = 0.f;
  #pragma unroll
  for (int s = 0; s < NVQ; ++s) {
    int w = (int)(wsl[b * NVQ + s] & 0xffffffffULL);
    z += emb[((size_t)s * NCODES + w) * LDIM + t];
  }
  z_s[t] = z;   // effective_z = sum of quantized codes (straight-through, eval)
  __syncthreads();
  float m1 = mod_b[l * 2 * HID + t];
  float m2 = mod_b[l * 2 * HID + HID + t];
  const float* Wm = mod_W + (size_t)l * LDIM * 2 * HID;
  #pragma unroll 4
  for (int d = 0; d < LDIM; ++d) {
    float zd = z_s[d];
    m1 = fmaf(zd, Wm[d * 2 * HID + t], m1);
    m2 = fmaf(zd, Wm[d * 2 * HID + HID + t], m2);
  }
  float* film = ws + FILM_OFF;
  film[((b * 4 + li) * 2 + 0) * HID + t] = 1.f + m1;
  film[((b * 4 + li) * 2 + 1) * HID + t] = m2;
}

// ---------------- prep_w: transpose + split W into bf16 hi/lo short planes ----------------
__global__ __launch_bounds__(256) void prep_w(const float* __restrict__ Whg,
                                              float* __restrict__ ws) {
  __shared__ float st[64][257];
  const int t = threadIdx.x;
  const int li = blockIdx.x & 3;
  const int kc0 = (blockIdx.x >> 2) * 64;
  for (int r = 0; r < 64; ++r)
    st[r][t] = Whg[((size_t)(li * 256 + kc0 + r)) * 256 + t];
  __syncthreads();
  short* wp_hi = (short*)((char*)ws + WP_BYTE);
  short* wp_lo = wp_hi + 4 * 256 * 256;
  const size_t base = ((size_t)(li * 256 + t)) * 256 + kc0;
  for (int i0 = 0; i0 < 64; i0 += 8) {
    short8 hv, lv;
    #pragma unroll
    for (int j = 0; j < 8; ++j) {
      short hi, lo;
      split_trunc(st[i0 + j][t], hi, lo);
      hv[j] = hi; lv[j] = lo;
    }
    *(short8*)&wp_hi[base + i0] = hv;
    *(short8*)&wp_lo[base + i0] = lv;
  }
}

// ---------------- FAST siren: hi/lo short planes in LDS, B planes from ws/L2 ----------------
__global__ __launch_bounds__(512) void siren_mfma_fast(
    const float* __restrict__ coords,
    const float* __restrict__ W0,
    const float* __restrict__ b0,
    const float* __restrict__ bhv,
    const float* __restrict__ Wl,
    const float* __restrict__ bl,
    const float* __restrict__ ws,
    float* __restrict__ out) {
  __shared__ short x_h[128 * 264];   // 67,584 B (row stride 264: 2-way banks only)
  __shared__ short x_l[128 * 264];   // 67,584 B
  __shared__ float osum[128 * 4 * 3];
  const int tid = threadIdx.x;
  const int bp = blockIdx.x;
  const int b = bp >> 5;
  const int tile = bp & 31;
  const int pbase = b * NPTS + tile * PTILE;

  // ---- layer 0 ----
  {
    const int quarter = tid >> 7;
    const int p = tid & 127;
    const float c0 = coords[(size_t)(pbase + p) * 2 + 0];
    const float c1 = coords[(size_t)(pbase + p) * 2 + 1];
    const int d0 = quarter * 64;
    for (int i = 0; i < 64; i += 8) {
      short8 hv, lv;
      #pragma unroll
      for (int j = 0; j < 8; ++j) {
        int d = d0 + i + j;
        float pre = fmaf(c0, W0[d], fmaf(c1, W0[HID + d], b0[d]));
        short hi, lo;
        split_trunc(__sinf(OMEGA_ * pre), hi, lo);
        hv[j] = hi; lv[j] = lo;
      }
      *(short8*)&x_h[p * 264 + d0 + i] = hv;
      *(short8*)&x_l[p * 264 + d0 + i] = lv;
    }
  }

  const int lane = tid & 63;
  const int wv = tid >> 6;
  const int pg = wv & 1;
  const int hq = wv >> 1;
  const int pb = pg * 64;
  const int hb = hq * 64;
  const int n = lane & 15;
  const int q = lane >> 4;

  const short* wp_hi = (const short*)((const char*)ws + WP_BYTE);
  const short* wp_lo = wp_hi + 4 * 256 * 256;
  const float* film = ws + FILM_OFF;

  for (int layer = 1; layer < NLAY; ++layer) {
    const int li = layer - 1;
    f32x4 acc[4][4];
    #pragma unroll
    for (int pt = 0; pt < 4; ++pt)
      #pragma unroll
      for (int ht = 0; ht < 4; ++ht)
        acc[pt][ht] = (f32x4){0.f, 0.f, 0.f, 0.f};

    __syncthreads();

    #pragma unroll 2
    for (int kc = 0; kc < HID; kc += 32) {
      short8 Bh[4], Bl[4];
      #pragma unroll
      for (int ht = 0; ht < 4; ++ht) {
        const size_t wb = ((size_t)(li * 256 + hb + ht * 16 + n)) * 256 + kc + q * 8;
        Bh[ht] = *(const short8*)&wp_hi[wb];
        Bl[ht] = *(const short8*)&wp_lo[wb];
      }
      short8 Ah[4], Al[4];
      #pragma unroll
      for (int pt = 0; pt < 4; ++pt) {
        const int xb = (pb + pt * 16 + n) * 264 + kc + q * 8;
        Ah[pt] = *(const short8*)&x_h[xb];
        Al[pt] = *(const short8*)&x_l[xb];
      }
      #pragma unroll
      for (int ht = 0; ht < 4; ++ht) {
        #pragma unroll
        for (int pt = 0; pt < 4; ++pt) {
          acc[pt][ht] = __builtin_amdgcn_mfma_f32_16x16x32_bf16(Ah[pt], Bh[ht], acc[pt][ht], 0, 0, 0);
          acc[pt][ht] = __builtin_amdgcn_mfma_f32_16x16x32_bf16(Ah[pt], Bl[ht], acc[pt][ht], 0, 0, 0);
          acc[pt][ht] = __builtin_amdgcn_mfma_f32_16x16x32_bf16(Al[pt], Bh[ht], acc[pt][ht], 0, 0, 0);
        }
      }
    }

    __syncthreads();

    // epilogue: D layout col=lane&15 (h), row=q*4+r (p)
    #pragma unroll
    for (int ht = 0; ht < 4; ++ht) {
      const int h = hb + ht * 16 + n;
      const float bias = bhv[li * HID + h];
      const float g1 = film[((b * 4 + li) * 2 + 0) * HID + h];
      const float bt = film[((b * 4 + li) * 2 + 1) * HID + h];
      #pragma unroll
      for (int pt = 0; pt < 4; ++pt) {
        #pragma unroll
        for (int r = 0; r < 4; ++r) {
          float pre = acc[pt][ht][r] + bias;
          pre = fmaf(pre, g1, bt);
          short hi, lo;
          split_trunc(__sinf(OMEGA_ * pre), hi, lo);
          const int row = pb + pt * 16 + q * 4 + r;
          x_h[row * 264 + h] = hi;
          x_l[row * 264 + h] = lo;
        }
      }
    }
  }
  __syncthreads();

  // ---- output layer ----
  {
    const int p = tid >> 2;
    const int dq = tid & 3;
    float v0 = 0.f, v1 = 0.f, v2 = 0.f;
    for (int i = 0; i < 64; ++i) {
      int d = dq * 64 + i;
      float xv = bf16_hi_f((unsigned short)x_h[p * 264 + d]) +
                 bf16_hi_f((unsigned short)x_l[p * 264 + d]);
      v0 = fmaf(xv, Wl[d * 3 + 0], v0);
      v1 = fmaf(xv, Wl[d * 3 + 1], v1);
      v2 = fmaf(xv, Wl[d * 3 + 2], v2);
    }
    osum[(p * 4 + dq) * 3 + 0] = v0;
    osum[(p * 4 + dq) * 3 + 1] = v1;
    osum[(p * 4 + dq) * 3 + 2] = v2;
  }
  __syncthreads();
  if (tid < PTILE) {
    const int p = tid;
    float v[3] = {bl[0], bl[1], bl[2]};
    #pragma unroll
    for (int dq = 0; dq < 4; ++dq)
      #pragma unroll
      for (int c = 0; c < 3; ++c) v[c] += osum[(p * 4 + dq) * 3 + c];
    size_t o = (size_t)(pbase + p) * 3;
    out[o + 0] = v[0]; out[o + 1] = v[1]; out[o + 2] = v[2];
  }
}

// ---------------- FALLBACK siren: byte-equivalent to round-8 (proven) ----------------
__global__ __launch_bounds__(512) void siren_mfma(
    const float* __restrict__ coords,
    const float* __restrict__ W0,
    const float* __restrict__ b0,
    const float* __restrict__ Whg,
    const float* __restrict__ bhv,
    const float* __restrict__ Wl,
    const float* __restrict__ bl,
    const float* __restrict__ ws,
    float* __restrict__ out) {
  __shared__ unsigned int x_u[128 * 260];
  __shared__ float osum[128 * 4 * 3];
  const int tid = threadIdx.x;
  const int bp = blockIdx.x;
  const int b = bp >> 5;
  const int tile = bp & 31;
  const int pbase = b * NPTS + tile * PTILE;
  {
    const int quarter = tid >> 7;
    const int p = tid & 127;
    const float c0 = coords[(size_t)(pbase + p) * 2 + 0];
    const float c1 = coords[(size_t)(pbase + p) * 2 + 1];
    const int d0 = quarter * 64;
    for (int i = 0; i < 64; i += 4) {
      unsigned int buf[4];
      #pragma unroll
      for (int j = 0; j < 4; ++j) {
        int d = d0 + i + j;
        float pre = fmaf(c0, W0[d], fmaf(c1, W0[HID + d], b0[d]));
        buf[j] = pack_split(__sinf(OMEGA_ * pre));
      }
      *(uint4*)&x_u[p * 260 + d0 + i] = *(uint4*)buf;
    }
  }
  const int lane = tid & 63;
  const int wv = tid >> 6;
  const int pg = wv & 1;
  const int hq = wv >> 1;
  const int pb = pg * 64;
  const int hb = hq * 64;
  const int n = lane & 15;
  const int q = lane >> 4;
  const float* film = ws + FILM_OFF;
  for (int layer = 1; layer < NLAY; ++layer) {
    const int li = layer - 1;
    f32x4 acc[4][4];
    #pragma unroll
    for (int pt = 0; pt < 4; ++pt)
      #pragma unroll
      for (int ht = 0; ht < 4; ++ht)
        acc[pt][ht] = (f32x4){0.f, 0.f, 0.f, 0.f};
    __syncthreads();
    for (int kc = 0; kc < HID; kc += 32) {
      short8 Bh[4], Bl[4];
      #pragma unroll
      for (int ht = 0; ht < 4; ++ht) {
        const float* wbase = Whg + ((size_t)(li * 256 + kc + q * 8)) * 256 + hb + ht * 16 + n;
        #pragma unroll
        for (int j = 0; j < 8; ++j) {
          short hi, lo;
          split_trunc(wbase[(size_t)j * 256], hi, lo);
          Bh[ht][j] = hi; Bl[ht][j] = lo;
        }
      }
      short8 ah[4], al[4];
      #pragma unroll
      for (int pt = 0; pt < 4; ++pt) {
        const uint4* ap = (const uint4*)&x_u[(pb + pt * 16 + n) * 260 + kc + q * 8];
        uint4 a0 = ap[0], a1 = ap[1];
        unsigned int aw[8] = {a0.x, a0.y, a0.z, a0.w, a1.x, a1.y, a1.z, a1.w};
        #pragma unroll
        for (int j = 0; j < 8; ++j) {
          ah[pt][j] = (short)(aw[j] >> 16);
          al[pt][j] = (short)(aw[j] & 0xffffu);
        }
      }
      #pragma unroll
      for (int ht = 0; ht < 4; ++ht) {
        #pragma unroll
        for (int pt = 0; pt < 4; ++pt) {
          acc[pt][ht] = __builtin_amdgcn_mfma_f32_16x16x32_bf16(ah[pt], Bh[ht], acc[pt][ht], 0, 0, 0);
          acc[pt][ht] = __builtin_amdgcn_mfma_f32_16x16x32_bf16(ah[pt], Bl[ht], acc[pt][ht], 0, 0, 0);
          acc[pt][ht] = __builtin_amdgcn_mfma_f32_16x16x32_bf16(al[pt], Bh[ht], acc[pt][ht], 0, 0, 0);
        }
      }
    }
    __syncthreads();
    #pragma unroll
    for (int ht = 0; ht < 4; ++ht) {
      const int h = hb + ht * 16 + n;
      const float bias = bhv[li * HID + h];
      const float g1 = film[((b * 4 + li) * 2 + 0) * HID + h];
      const float bt = film[((b * 4 + li) * 2 + 1) * HID + h];
      #pragma unroll
      for (int pt = 0; pt < 4; ++pt) {
        #pragma unroll
        for (int r = 0; r < 4; ++r) {
          float pre = acc[pt][ht][r] + bias;
          pre = fmaf(pre, g1, bt);
          x_u[(pb + pt * 16 + q * 4 + r) * 260 + h] = pack_split(__sinf(OMEGA_ * pre));
        }
      }
    }
  }
  __syncthreads();
  {
    const int p = tid >> 2;
    const int dq = tid & 3;
    float v0 = 0.f, v1 = 0.f, v2 = 0.f;
    for (int i = 0; i < 64; ++i) {
      int d = dq * 64 + i;
      unsigned int wrd = x_u[p * 260 + d];
      float xv = bf16_hi_f((unsigned short)(wrd >> 16)) +
                 bf16_hi_f((unsigned short)(wrd & 0xffffu));
      v0 = fmaf(xv, Wl[d * 3 + 0], v0);
      v1 = fmaf(xv, Wl[d * 3 + 1], v1);
      v2 = fmaf(xv, Wl[d * 3 + 2], v2);
    }
    osum[(p * 4 + dq) * 3 + 0] = v0;
    osum[(p * 4 + dq) * 3 + 1] = v1;
    osum[(p * 4 + dq) * 3 + 2] = v2;
  }
  __syncthreads();
  if (tid < PTILE) {
    const int p = tid;
    float v[3] = {bl[0], bl[1], bl[2]};
    #pragma unroll
    for (int dq = 0; dq < 4; ++dq)
      #pragma unroll
      for (int c = 0; c < 3; ++c) v[c] += osum[(p * 4 + dq) * 3 + c];
    size_t o = (size_t)(pbase + p) * 3;
    out[o + 0] = v[0]; out[o + 1] = v[1]; out[o + 2] = v[2];
  }
}

extern "C" void kernel_launch(void* const* d_in, const int* in_sizes, int n_in,
                              void* d_out, int out_size, void* d_ws, size_t ws_size,
                              hipStream_t stream) {
  (void)in_sizes; (void)n_in;
  const float* coords  = (const float*)d_in[0];
  const int*   lidx    = (const int*)d_in[1];
  const float* latents = (const float*)d_in[2];
  const float* emb     = (const float*)d_in[3];
  const float* mod_W   = (const float*)d_in[4];
  const float* mod_b   = (const float*)d_in[5];
  const float* W0      = (const float*)d_in[6];
  const float* b0      = (const float*)d_in[7];
  const float* Wh      = (const float*)d_in[8];
  const float* bh      = (const float*)d_in[9];
  const float* Wl      = (const float*)d_in[10];
  const float* bl      = (const float*)d_in[11];
  float* out = (float*)d_out;
  float* ws  = (float*)d_ws;
  float* loss_out = out + (out_size - 1);

  const bool fast = (ws_size >= FAST_WS_NEEDED);   // constant per harness -> graph-safe
  if (fast) prep_w<<<16, 256, 0, stream>>>(Wh, ws);
  vq_init<<<BATCH, 256, 0, stream>>>(lidx, latents, ws);
  for (int s = 0; s < NVQ; ++s)
    vq_stage<<<BATCH * 8, 256, 0, stream>>>(emb, ws, s);
  vq_loss<<<1, 256, 0, stream>>>(emb, ws, loss_out);
  film_kernel<<<BATCH * 4, 256, 0, stream>>>(emb, mod_W, mod_b, ws);
  if (fast)
    siren_mfma_fast<<<(BATCH * NPTS) / PTILE, 512, 0, stream>>>(coords, W0, b0, bh, Wl, bl, ws, out);
  else
    siren_mfma<<<(BATCH * NPTS) / PTILE, 512, 0, stream>>>(coords, W0, b0, Wh, bh, Wl, bl, ws, out);
}

// Round 10
// 256.769 us; speedup vs baseline: 1.2496x; 1.2496x over previous
//
#include <hip/hip_runtime.h>
#include <math.h>

#define LDIM 256
#define NCODES 1024
#define HID 256
#define NLAY 5
#define NVQ 4
#define CC_ 0.25f
#define OMEGA_ 30.0f
#define BATCH 16
#define NPTS 4096
#define PTILE 128

// ws layout (bytes):
//   [0      .. 16383 ] z per batch (16x256 f32)
//   [16384  .. 16895 ] winners: 16 batches x 4 stages u64, packed (mono_dist<<32)|idx
//   [32768  .. 163839] FiLM params
//   fast path only (ws_size >= 1,245,184):
//   [196608 .. 720895 ] wpf_hi: bf16 hi plane, fragment-linear [li][htile16][kc8][lane64][8]
//   [720896 .. 1245183] wpf_lo: bf16 lo plane, same order
#define WIN_OFF 4096
#define FILM_OFF 8192
#define WP_BYTE 196608
#define PLANE_SHORTS (4 * 16 * 8 * 64 * 8)   // 262144 shorts = 512 KB
#define FAST_WS_NEEDED 1245184u

typedef __attribute__((ext_vector_type(8))) short short8;
typedef __attribute__((ext_vector_type(4))) float f32x4;

__device__ __forceinline__ unsigned int pack_split(float x) {
  unsigned int u = __builtin_bit_cast(unsigned int, x);
  float hf = __builtin_bit_cast(float, u & 0xffff0000u);
  float lf = x - hf;
  unsigned int ul = __builtin_bit_cast(unsigned int, lf);
  return (u & 0xffff0000u) | (ul >> 16);
}
__device__ __forceinline__ void split_trunc(float x, short& hi, short& lo) {
  unsigned int u = __builtin_bit_cast(unsigned int, x);
  float hf = __builtin_bit_cast(float, u & 0xffff0000u);
  float lf = x - hf;
  hi = (short)(u >> 16);
  lo = (short)(__builtin_bit_cast(unsigned int, lf) >> 16);
}
__device__ __forceinline__ float bf16_hi_f(unsigned short h) {
  return __builtin_bit_cast(float, (unsigned int)h << 16);
}
__device__ __forceinline__ unsigned int mono_u32(float f) {
  unsigned int u = __builtin_bit_cast(unsigned int, f);
  return (u & 0x80000000u) ? ~u : (u | 0x80000000u);
}

// ---------------- VQ init ----------------
__global__ __launch_bounds__(256) void vq_init(const int* __restrict__ lidx,
                                               const float* __restrict__ latents,
                                               float* __restrict__ ws) {
  const int t = threadIdx.x, b = blockIdx.x;
  const int ib = lidx[b];
  float z = 0.f;
  #pragma unroll
  for (int v = 0; v < NVQ; ++v) z += latents[((size_t)ib * NVQ + v) * LDIM + t];
  ws[b * LDIM + t] = z;
  if (t < NVQ) ((unsigned long long*)(ws + WIN_OFF))[b * NVQ + t] = ~0ULL;
}

// ---------------- VQ stage (proven r9) ----------------
__global__ __launch_bounds__(256) void vq_stage(const float* __restrict__ emb,
                                                float* __restrict__ ws, int stage) {
  __shared__ __align__(16) float Ech[32 * 260];
  __shared__ __align__(16) float r_s[LDIM];
  __shared__ float mval[256];
  __shared__ int   midx[256];
  const int t = threadIdx.x;
  const int b = blockIdx.x >> 3;
  const int slice = blockIdx.x & 7;
  const unsigned long long* wsl = (const unsigned long long*)(ws + WIN_OFF);
  float r = ws[b * LDIM + t];
  for (int j = 0; j < stage; ++j) {
    int wj = (int)(wsl[b * NVQ + j] & 0xffffffffULL);
    r -= emb[((size_t)j * NCODES + wj) * LDIM + t];
  }
  r_s[t] = r;
  __syncthreads();
  const float* E = emb + (size_t)stage * NCODES * LDIM + (size_t)slice * 128 * LDIM;
  const float4* E4 = (const float4*)E;
  const int cg = t >> 3;
  const int dq = t & 7;
  float bestv = 3.4e38f; int besti = 0;
  for (int ch = 0; ch < 4; ++ch) {
    __syncthreads();
    #pragma unroll
    for (int it = 0; it < 8; ++it) {
      int f = it * 256 + t;
      int row = f >> 6;
      int col4 = f & 63;
      *(float4*)&Ech[row * 260 + col4 * 4] = E4[(size_t)(ch * 32 + row) * 64 + col4];
    }
    __syncthreads();
    float dot = 0.f, e2 = 0.f;
    const float* er = &Ech[cg * 260];
    const float4* rr4 = (const float4*)r_s;
    #pragma unroll
    for (int j = 0; j < 8; ++j) {
      int d4 = dq + 8 * j;
      float4 e = *(const float4*)&er[d4 * 4];
      float4 rv = rr4[d4];
      dot += e.x * rv.x + e.y * rv.y + e.z * rv.z + e.w * rv.w;
      e2  += e.x * e.x + e.y * e.y + e.z * e.z + e.w * e.w;
    }
    dot += __shfl_xor(dot, 1); e2 += __shfl_xor(e2, 1);
    dot += __shfl_xor(dot, 2); e2 += __shfl_xor(e2, 2);
    dot += __shfl_xor(dot, 4); e2 += __shfl_xor(e2, 4);
    if (dq == 0) {
      float dist = e2 - 2.f * dot;
      int c = slice * 128 + ch * 32 + cg;
      if (dist < bestv) { bestv = dist; besti = c; }
    }
  }
  mval[t] = (dq == 0) ? bestv : 3.4e38f;
  midx[t] = (dq == 0) ? besti : (1 << 30);
  __syncthreads();
  for (int off = 128; off > 0; off >>= 1) {
    if (t < off) {
      float ov = mval[t + off]; int oi = midx[t + off];
      if (ov < mval[t] || (ov == mval[t] && oi < midx[t])) { mval[t] = ov; midx[t] = oi; }
    }
    __syncthreads();
  }
  if (t == 0) {
    unsigned long long pack =
        ((unsigned long long)mono_u32(mval[0]) << 32) | (unsigned int)midx[0];
    atomicMin((unsigned long long*)(ws + WIN_OFF) + (b * NVQ + stage), pack);
  }
}

// ---------------- FiLM params + loss (grid 65: blocks 0..63 film, 64 loss) ----------------
__global__ __launch_bounds__(256) void film_loss(const float* __restrict__ emb,
                                                 const float* __restrict__ mod_W,
                                                 const float* __restrict__ mod_b,
                                                 float* __restrict__ ws,
                                                 float* __restrict__ loss_out) {
  __shared__ float z_s[LDIM];
  const int t = threadIdx.x;
  const unsigned long long* wsl = (const unsigned long long*)(ws + WIN_OFF);
  if (blockIdx.x == 64) {   // loss block
    __shared__ float red[256];
    float acc = 0.f;
    for (int b = 0; b < BATCH; ++b) {
      float r = ws[b * LDIM + t];
      #pragma unroll
      for (int s = 0; s < NVQ; ++s) {
        int w = (int)(wsl[b * NVQ + s] & 0xffffffffULL);
        float e = emb[((size_t)s * NCODES + w) * LDIM + t];
        float d = e - r;
        acc += d * d;
        r -= e;
      }
    }
    red[t] = acc;
    __syncthreads();
    for (int off = 128; off > 0; off >>= 1) {
      if (t < off) red[t] += red[t + off];
      __syncthreads();
    }
    if (t == 0) loss_out[0] = red[0] * (CC_ / (NVQ * BATCH * LDIM));
    return;
  }
  const int li = blockIdx.x & 3;
  const int b  = blockIdx.x >> 2;
  const int l  = li + 1;
  float z = 0.f;
  #pragma unroll
  for (int s = 0; s < NVQ; ++s) {
    int w = (int)(wsl[b * NVQ + s] & 0xffffffffULL);
    z += emb[((size_t)s * NCODES + w) * LDIM + t];
  }
  z_s[t] = z;
  __syncthreads();
  float m1 = mod_b[l * 2 * HID + t];
  float m2 = mod_b[l * 2 * HID + HID + t];
  const float* Wm = mod_W + (size_t)l * LDIM * 2 * HID;
  #pragma unroll 4
  for (int d = 0; d < LDIM; ++d) {
    float zd = z_s[d];
    m1 = fmaf(zd, Wm[d * 2 * HID + t], m1);
    m2 = fmaf(zd, Wm[d * 2 * HID + HID + t], m2);
  }
  float* film = ws + FILM_OFF;
  film[((b * 4 + li) * 2 + 0) * HID + t] = 1.f + m1;
  film[((b * 4 + li) * 2 + 1) * HID + t] = m2;
}

// ---------------- prep_w: W -> fragment-linear hi/lo planes ----------------
// wpf[li][h_t][c][lane=q*16+n][j] = split(W[li][k=c*32+q*8+j][h=h_t*16+n])
__global__ __launch_bounds__(256) void prep_w(const float* __restrict__ Whg,
                                              float* __restrict__ ws) {
  const int li = blockIdx.x >> 3;   // 0..3
  const int c  = blockIdx.x & 7;    // kc chunk 0..7
  const int t = threadIdx.x;
  const int lane = t & 63;
  const int n = lane & 15, q = lane >> 4;
  short* wp_hi = (short*)((char*)ws + WP_BYTE);
  short* wp_lo = wp_hi + PLANE_SHORTS;
  for (int h_t = (t >> 6); h_t < 16; h_t += 4) {
    short8 hv, lv;
    #pragma unroll
    for (int j = 0; j < 8; ++j) {
      float x = Whg[((size_t)(li * 256 + c * 32 + q * 8 + j)) * 256 + h_t * 16 + n];
      short hi, lo;
      split_trunc(x, hi, lo);
      hv[j] = hi; lv[j] = lo;
    }
    size_t off = ((((size_t)li * 16 + h_t) * 8 + c) * 64 + lane) * 8;
    *(short8*)&wp_hi[off] = hv;
    *(short8*)&wp_lo[off] = lv;
  }
}

// ---------------- FAST siren: fragment-linear B (coalesced), hi/lo LDS planes ----------------
__global__ __launch_bounds__(512) void siren_mfma_fast(
    const float* __restrict__ coords,
    const float* __restrict__ W0,
    const float* __restrict__ b0,
    const float* __restrict__ bhv,
    const float* __restrict__ Wl,
    const float* __restrict__ bl,
    const float* __restrict__ ws,
    float* __restrict__ out) {
  __shared__ short x_h[128 * 264];
  __shared__ short x_l[128 * 264];
  __shared__ float osum[128 * 4 * 3];
  const int tid = threadIdx.x;
  const int bp = blockIdx.x;
  const int b = bp >> 5;
  const int tile = bp & 31;
  const int pbase = b * NPTS + tile * PTILE;

  {
    const int quarter = tid >> 7;
    const int p = tid & 127;
    const float c0 = coords[(size_t)(pbase + p) * 2 + 0];
    const float c1 = coords[(size_t)(pbase + p) * 2 + 1];
    const int d0 = quarter * 64;
    for (int i = 0; i < 64; i += 8) {
      short8 hv, lv;
      #pragma unroll
      for (int j = 0; j < 8; ++j) {
        int d = d0 + i + j;
        float pre = fmaf(c0, W0[d], fmaf(c1, W0[HID + d], b0[d]));
        short hi, lo;
        split_trunc(__sinf(OMEGA_ * pre), hi, lo);
        hv[j] = hi; lv[j] = lo;
      }
      *(short8*)&x_h[p * 264 + d0 + i] = hv;
      *(short8*)&x_l[p * 264 + d0 + i] = lv;
    }
  }

  const int lane = tid & 63;
  const int wv = tid >> 6;
  const int pg = wv & 1;
  const int hq = wv >> 1;
  const int pb = pg * 64;
  const int hb = hq * 64;
  const int n = lane & 15;
  const int q = lane >> 4;

  const short* wp_hi = (const short*)((const char*)ws + WP_BYTE);
  const short* wp_lo = wp_hi + PLANE_SHORTS;
  const float* film = ws + FILM_OFF;

  for (int layer = 1; layer < NLAY; ++layer) {
    const int li = layer - 1;
    f32x4 acc[4][4];
    #pragma unroll
    for (int pt = 0; pt < 4; ++pt)
      #pragma unroll
      for (int ht = 0; ht < 4; ++ht)
        acc[pt][ht] = (f32x4){0.f, 0.f, 0.f, 0.f};

    __syncthreads();

    #pragma unroll 2
    for (int kc = 0; kc < HID; kc += 32) {
      const int c = kc >> 5;
      short8 Bh[4], Bl[4];
      #pragma unroll
      for (int ht = 0; ht < 4; ++ht) {
        // fragment-linear: one contiguous 1 KB per wave -> fully coalesced
        const size_t wb = ((((size_t)li * 16 + hq * 4 + ht) * 8 + c) * 64 + lane) * 8;
        Bh[ht] = *(const short8*)&wp_hi[wb];
        Bl[ht] = *(const short8*)&wp_lo[wb];
      }
      short8 Ah[4], Al[4];
      #pragma unroll
      for (int pt = 0; pt < 4; ++pt) {
        const int xb = (pb + pt * 16 + n) * 264 + kc + q * 8;
        Ah[pt] = *(const short8*)&x_h[xb];
        Al[pt] = *(const short8*)&x_l[xb];
      }
      #pragma unroll
      for (int ht = 0; ht < 4; ++ht) {
        #pragma unroll
        for (int pt = 0; pt < 4; ++pt) {
          acc[pt][ht] = __builtin_amdgcn_mfma_f32_16x16x32_bf16(Ah[pt], Bh[ht], acc[pt][ht], 0, 0, 0);
          acc[pt][ht] = __builtin_amdgcn_mfma_f32_16x16x32_bf16(Ah[pt], Bl[ht], acc[pt][ht], 0, 0, 0);
          acc[pt][ht] = __builtin_amdgcn_mfma_f32_16x16x32_bf16(Al[pt], Bh[ht], acc[pt][ht], 0, 0, 0);
        }
      }
    }

    __syncthreads();

    #pragma unroll
    for (int ht = 0; ht < 4; ++ht) {
      const int h = hb + ht * 16 + n;
      const float bias = bhv[li * HID + h];
      const float g1 = film[((b * 4 + li) * 2 + 0) * HID + h];
      const float bt = film[((b * 4 + li) * 2 + 1) * HID + h];
      #pragma unroll
      for (int pt = 0; pt < 4; ++pt) {
        #pragma unroll
        for (int r = 0; r < 4; ++r) {
          float pre = acc[pt][ht][r] + bias;
          pre = fmaf(pre, g1, bt);
          short hi, lo;
          split_trunc(__sinf(OMEGA_ * pre), hi, lo);
          const int row = pb + pt * 16 + q * 4 + r;
          x_h[row * 264 + h] = hi;
          x_l[row * 264 + h] = lo;
        }
      }
    }
  }
  __syncthreads();

  {
    const int p = tid >> 2;
    const int dq = tid & 3;
    float v0 = 0.f, v1 = 0.f, v2 = 0.f;
    for (int i = 0; i < 64; ++i) {
      int d = dq * 64 + i;
      float xv = bf16_hi_f((unsigned short)x_h[p * 264 + d]) +
                 bf16_hi_f((unsigned short)x_l[p * 264 + d]);
      v0 = fmaf(xv, Wl[d * 3 + 0], v0);
      v1 = fmaf(xv, Wl[d * 3 + 1], v1);
      v2 = fmaf(xv, Wl[d * 3 + 2], v2);
    }
    osum[(p * 4 + dq) * 3 + 0] = v0;
    osum[(p * 4 + dq) * 3 + 1] = v1;
    osum[(p * 4 + dq) * 3 + 2] = v2;
  }
  __syncthreads();
  if (tid < PTILE) {
    const int p = tid;
    float v[3] = {bl[0], bl[1], bl[2]};
    #pragma unroll
    for (int dq = 0; dq < 4; ++dq)
      #pragma unroll
      for (int c = 0; c < 3; ++c) v[c] += osum[(p * 4 + dq) * 3 + c];
    size_t o = (size_t)(pbase + p) * 3;
    out[o + 0] = v[0]; out[o + 1] = v[1]; out[o + 2] = v[2];
  }
}

// ---------------- FALLBACK siren (round-8-proven, B direct from Wh) ----------------
__global__ __launch_bounds__(512) void siren_mfma(
    const float* __restrict__ coords,
    const float* __restrict__ W0,
    const float* __restrict__ b0,
    const float* __restrict__ Whg,
    const float* __restrict__ bhv,
    const float* __restrict__ Wl,
    const float* __restrict__ bl,
    const float* __restrict__ ws,
    float* __restrict__ out) {
  __shared__ unsigned int x_u[128 * 260];
  __shared__ float osum[128 * 4 * 3];
  const int tid = threadIdx.x;
  const int bp = blockIdx.x;
  const int b = bp >> 5;
  const int tile = bp & 31;
  const int pbase = b * NPTS + tile * PTILE;
  {
    const int quarter = tid >> 7;
    const int p = tid & 127;
    const float c0 = coords[(size_t)(pbase + p) * 2 + 0];
    const float c1 = coords[(size_t)(pbase + p) * 2 + 1];
    const int d0 = quarter * 64;
    for (int i = 0; i < 64; i += 4) {
      unsigned int buf[4];
      #pragma unroll
      for (int j = 0; j < 4; ++j) {
        int d = d0 + i + j;
        float pre = fmaf(c0, W0[d], fmaf(c1, W0[HID + d], b0[d]));
        buf[j] = pack_split(__sinf(OMEGA_ * pre));
      }
      *(uint4*)&x_u[p * 260 + d0 + i] = *(uint4*)buf;
    }
  }
  const int lane = tid & 63;
  const int wv = tid >> 6;
  const int pg = wv & 1;
  const int hq = wv >> 1;
  const int pb = pg * 64;
  const int hb = hq * 64;
  const int n = lane & 15;
  const int q = lane >> 4;
  const float* film = ws + FILM_OFF;
  for (int layer = 1; layer < NLAY; ++layer) {
    const int li = layer - 1;
    f32x4 acc[4][4];
    #pragma unroll
    for (int pt = 0; pt < 4; ++pt)
      #pragma unroll
      for (int ht = 0; ht < 4; ++ht)
        acc[pt][ht] = (f32x4){0.f, 0.f, 0.f, 0.f};
    __syncthreads();
    for (int kc = 0; kc < HID; kc += 32) {
      short8 Bh[4], Bl[4];
      #pragma unroll
      for (int ht = 0; ht < 4; ++ht) {
        const float* wbase = Whg + ((size_t)(li * 256 + kc + q * 8)) * 256 + hb + ht * 16 + n;
        #pragma unroll
        for (int j = 0; j < 8; ++j) {
          short hi, lo;
          split_trunc(wbase[(size_t)j * 256], hi, lo);
          Bh[ht][j] = hi; Bl[ht][j] = lo;
        }
      }
      short8 ah[4], al[4];
      #pragma unroll
      for (int pt = 0; pt < 4; ++pt) {
        const uint4* ap = (const uint4*)&x_u[(pb + pt * 16 + n) * 260 + kc + q * 8];
        uint4 a0 = ap[0], a1 = ap[1];
        unsigned int aw[8] = {a0.x, a0.y, a0.z, a0.w, a1.x, a1.y, a1.z, a1.w};
        #pragma unroll
        for (int j = 0; j < 8; ++j) {
          ah[pt][j] = (short)(aw[j] >> 16);
          al[pt][j] = (short)(aw[j] & 0xffffu);
        }
      }
      #pragma unroll
      for (int ht = 0; ht < 4; ++ht) {
        #pragma unroll
        for (int pt = 0; pt < 4; ++pt) {
          acc[pt][ht] = __builtin_amdgcn_mfma_f32_16x16x32_bf16(ah[pt], Bh[ht], acc[pt][ht], 0, 0, 0);
          acc[pt][ht] = __builtin_amdgcn_mfma_f32_16x16x32_bf16(ah[pt], Bl[ht], acc[pt][ht], 0, 0, 0);
          acc[pt][ht] = __builtin_amdgcn_mfma_f32_16x16x32_bf16(al[pt], Bh[ht], acc[pt][ht], 0, 0, 0);
        }
      }
    }
    __syncthreads();
    #pragma unroll
    for (int ht = 0; ht < 4; ++ht) {
      const int h = hb + ht * 16 + n;
      const float bias = bhv[li * HID + h];
      const float g1 = film[((b * 4 + li) * 2 + 0) * HID + h];
      const float bt = film[((b * 4 + li) * 2 + 1) * HID + h];
      #pragma unroll
      for (int pt = 0; pt < 4; ++pt) {
        #pragma unroll
        for (int r = 0; r < 4; ++r) {
          float pre = acc[pt][ht][r] + bias;
          pre = fmaf(pre, g1, bt);
          x_u[(pb + pt * 16 + q * 4 + r) * 260 + h] = pack_split(__sinf(OMEGA_ * pre));
        }
      }
    }
  }
  __syncthreads();
  {
    const int p = tid >> 2;
    const int dq = tid & 3;
    float v0 = 0.f, v1 = 0.f, v2 = 0.f;
    for (int i = 0; i < 64; ++i) {
      int d = dq * 64 + i;
      unsigned int wrd = x_u[p * 260 + d];
      float xv = bf16_hi_f((unsigned short)(wrd >> 16)) +
                 bf16_hi_f((unsigned short)(wrd & 0xffffu));
      v0 = fmaf(xv, Wl[d * 3 + 0], v0);
      v1 = fmaf(xv, Wl[d * 3 + 1], v1);
      v2 = fmaf(xv, Wl[d * 3 + 2], v2);
    }
    osum[(p * 4 + dq) * 3 + 0] = v0;
    osum[(p * 4 + dq) * 3 + 1] = v1;
    osum[(p * 4 + dq) * 3 + 2] = v2;
  }
  __syncthreads();
  if (tid < PTILE) {
    const int p = tid;
    float v[3] = {bl[0], bl[1], bl[2]};
    #pragma unroll
    for (int dq = 0; dq < 4; ++dq)
      #pragma unroll
      for (int c = 0; c < 3; ++c) v[c] += osum[(p * 4 + dq) * 3 + c];
    size_t o = (size_t)(pbase + p) * 3;
    out[o + 0] = v[0]; out[o + 1] = v[1]; out[o + 2] = v[2];
  }
}

extern "C" void kernel_launch(void* const* d_in, const int* in_sizes, int n_in,
                              void* d_out, int out_size, void* d_ws, size_t ws_size,
                              hipStream_t stream) {
  (void)in_sizes; (void)n_in;
  const float* coords  = (const float*)d_in[0];
  const int*   lidx    = (const int*)d_in[1];
  const float* latents = (const float*)d_in[2];
  const float* emb     = (const float*)d_in[3];
  const float* mod_W   = (const float*)d_in[4];
  const float* mod_b   = (const float*)d_in[5];
  const float* W0      = (const float*)d_in[6];
  const float* b0      = (const float*)d_in[7];
  const float* Wh      = (const float*)d_in[8];
  const float* bh      = (const float*)d_in[9];
  const float* Wl      = (const float*)d_in[10];
  const float* bl      = (const float*)d_in[11];
  float* out = (float*)d_out;
  float* ws  = (float*)d_ws;
  float* loss_out = out + (out_size - 1);

  const bool fast = (ws_size >= FAST_WS_NEEDED);
  if (fast) prep_w<<<32, 256, 0, stream>>>(Wh, ws);
  vq_init<<<BATCH, 256, 0, stream>>>(lidx, latents, ws);
  for (int s = 0; s < NVQ; ++s)
    vq_stage<<<BATCH * 8, 256, 0, stream>>>(emb, ws, s);
  film_loss<<<BATCH * 4 + 1, 256, 0, stream>>>(emb, mod_W, mod_b, ws, loss_out);
  if (fast)
    siren_mfma_fast<<<(BATCH * NPTS) / PTILE, 512, 0, stream>>>(coords, W0, b0, bh, Wl, bl, ws, out);
  else
    siren_mfma<<<(BATCH * NPTS) / PTILE, 512, 0, stream>>>(coords, W0, b0, Wh, bh, Wl, bl, ws, out);
}

// Round 11
// 256.578 us; speedup vs baseline: 1.2505x; 1.0007x over previous
//
#include <hip/hip_runtime.h>
#include <math.h>

#define LDIM 256
#define NCODES 1024
#define HID 256
#define NLAY 5
#define NVQ 4
#define CC_ 0.25f
#define OMEGA_ 30.0f
#define BATCH 16
#define NPTS 4096
#define PTILE 128

// ws layout (bytes):
//   [0      .. 16383 ] z per batch (16x256 f32)
//   [16384  .. 16895 ] winners: 16 batches x 4 stages u64, packed (mono_dist<<32)|idx
//   [32768  .. 163839] FiLM params
//   fast path (ws_size >= 1,245,184 -- PROVEN present in r10: fast path executed):
//   [196608 .. 720895 ] wpf_hi: bf16 hi plane, fragment-linear [li][htile16][kc8][lane64][8]
//   [720896 .. 1245183] wpf_lo: bf16 lo plane, same order
#define WIN_OFF 4096
#define FILM_OFF 8192
#define WP_BYTE 196608
#define PLANE_SHORTS (4 * 16 * 8 * 64 * 8)   // 262144 shorts = 512 KB
#define FAST_WS_NEEDED 1245184u

typedef __attribute__((ext_vector_type(8))) short short8;
typedef __attribute__((ext_vector_type(4))) float f32x4;

__device__ __forceinline__ unsigned int pack_split(float x) {
  unsigned int u = __builtin_bit_cast(unsigned int, x);
  float hf = __builtin_bit_cast(float, u & 0xffff0000u);
  float lf = x - hf;
  unsigned int ul = __builtin_bit_cast(unsigned int, lf);
  return (u & 0xffff0000u) | (ul >> 16);
}
__device__ __forceinline__ void split_trunc(float x, short& hi, short& lo) {
  unsigned int u = __builtin_bit_cast(unsigned int, x);
  float hf = __builtin_bit_cast(float, u & 0xffff0000u);
  float lf = x - hf;
  hi = (short)(u >> 16);
  lo = (short)(__builtin_bit_cast(unsigned int, lf) >> 16);
}
__device__ __forceinline__ float bf16_hi_f(unsigned short h) {
  return __builtin_bit_cast(float, (unsigned int)h << 16);
}
__device__ __forceinline__ unsigned int mono_u32(float f) {
  unsigned int u = __builtin_bit_cast(unsigned int, f);
  return (u & 0x80000000u) ? ~u : (u | 0x80000000u);
}

// ---------------- VQ init ----------------
__global__ __launch_bounds__(256) void vq_init(const int* __restrict__ lidx,
                                               const float* __restrict__ latents,
                                               float* __restrict__ ws) {
  const int t = threadIdx.x, b = blockIdx.x;
  const int ib = lidx[b];
  float z = 0.f;
  #pragma unroll
  for (int v = 0; v < NVQ; ++v) z += latents[((size_t)ib * NVQ + v) * LDIM + t];
  ws[b * LDIM + t] = z;
  if (t < NVQ) ((unsigned long long*)(ws + WIN_OFF))[b * NVQ + t] = ~0ULL;
}

// ---------------- VQ stage (proven r9/r10) ----------------
__global__ __launch_bounds__(256) void vq_stage(const float* __restrict__ emb,
                                                float* __restrict__ ws, int stage) {
  __shared__ __align__(16) float Ech[32 * 260];
  __shared__ __align__(16) float r_s[LDIM];
  __shared__ float mval[256];
  __shared__ int   midx[256];
  const int t = threadIdx.x;
  const int b = blockIdx.x >> 3;
  const int slice = blockIdx.x & 7;
  const unsigned long long* wsl = (const unsigned long long*)(ws + WIN_OFF);
  float r = ws[b * LDIM + t];
  for (int j = 0; j < stage; ++j) {
    int wj = (int)(wsl[b * NVQ + j] & 0xffffffffULL);
    r -= emb[((size_t)j * NCODES + wj) * LDIM + t];
  }
  r_s[t] = r;
  __syncthreads();
  const float* E = emb + (size_t)stage * NCODES * LDIM + (size_t)slice * 128 * LDIM;
  const float4* E4 = (const float4*)E;
  const int cg = t >> 3;
  const int dq = t & 7;
  float bestv = 3.4e38f; int besti = 0;
  for (int ch = 0; ch < 4; ++ch) {
    __syncthreads();
    #pragma unroll
    for (int it = 0; it < 8; ++it) {
      int f = it * 256 + t;
      int row = f >> 6;
      int col4 = f & 63;
      *(float4*)&Ech[row * 260 + col4 * 4] = E4[(size_t)(ch * 32 + row) * 64 + col4];
    }
    __syncthreads();
    float dot = 0.f, e2 = 0.f;
    const float* er = &Ech[cg * 260];
    const float4* rr4 = (const float4*)r_s;
    #pragma unroll
    for (int j = 0; j < 8; ++j) {
      int d4 = dq + 8 * j;
      float4 e = *(const float4*)&er[d4 * 4];
      float4 rv = rr4[d4];
      dot += e.x * rv.x + e.y * rv.y + e.z * rv.z + e.w * rv.w;
      e2  += e.x * e.x + e.y * e.y + e.z * e.z + e.w * e.w;
    }
    dot += __shfl_xor(dot, 1); e2 += __shfl_xor(e2, 1);
    dot += __shfl_xor(dot, 2); e2 += __shfl_xor(e2, 2);
    dot += __shfl_xor(dot, 4); e2 += __shfl_xor(e2, 4);
    if (dq == 0) {
      float dist = e2 - 2.f * dot;
      int c = slice * 128 + ch * 32 + cg;
      if (dist < bestv) { bestv = dist; besti = c; }
    }
  }
  mval[t] = (dq == 0) ? bestv : 3.4e38f;
  midx[t] = (dq == 0) ? besti : (1 << 30);
  __syncthreads();
  for (int off = 128; off > 0; off >>= 1) {
    if (t < off) {
      float ov = mval[t + off]; int oi = midx[t + off];
      if (ov < mval[t] || (ov == mval[t] && oi < midx[t])) { mval[t] = ov; midx[t] = oi; }
    }
    __syncthreads();
  }
  if (t == 0) {
    unsigned long long pack =
        ((unsigned long long)mono_u32(mval[0]) << 32) | (unsigned int)midx[0];
    atomicMin((unsigned long long*)(ws + WIN_OFF) + (b * NVQ + stage), pack);
  }
}

// ---------------- FiLM params + loss (grid 65) ----------------
__global__ __launch_bounds__(256) void film_loss(const float* __restrict__ emb,
                                                 const float* __restrict__ mod_W,
                                                 const float* __restrict__ mod_b,
                                                 float* __restrict__ ws,
                                                 float* __restrict__ loss_out) {
  __shared__ float z_s[LDIM];
  const int t = threadIdx.x;
  const unsigned long long* wsl = (const unsigned long long*)(ws + WIN_OFF);
  if (blockIdx.x == 64) {
    __shared__ float red[256];
    float acc = 0.f;
    for (int b = 0; b < BATCH; ++b) {
      float r = ws[b * LDIM + t];
      #pragma unroll
      for (int s = 0; s < NVQ; ++s) {
        int w = (int)(wsl[b * NVQ + s] & 0xffffffffULL);
        float e = emb[((size_t)s * NCODES + w) * LDIM + t];
        float d = e - r;
        acc += d * d;
        r -= e;
      }
    }
    red[t] = acc;
    __syncthreads();
    for (int off = 128; off > 0; off >>= 1) {
      if (t < off) red[t] += red[t + off];
      __syncthreads();
    }
    if (t == 0) loss_out[0] = red[0] * (CC_ / (NVQ * BATCH * LDIM));
    return;
  }
  const int li = blockIdx.x & 3;
  const int b  = blockIdx.x >> 2;
  const int l  = li + 1;
  float z = 0.f;
  #pragma unroll
  for (int s = 0; s < NVQ; ++s) {
    int w = (int)(wsl[b * NVQ + s] & 0xffffffffULL);
    z += emb[((size_t)s * NCODES + w) * LDIM + t];
  }
  z_s[t] = z;
  __syncthreads();
  float m1 = mod_b[l * 2 * HID + t];
  float m2 = mod_b[l * 2 * HID + HID + t];
  const float* Wm = mod_W + (size_t)l * LDIM * 2 * HID;
  #pragma unroll 4
  for (int d = 0; d < LDIM; ++d) {
    float zd = z_s[d];
    m1 = fmaf(zd, Wm[d * 2 * HID + t], m1);
    m2 = fmaf(zd, Wm[d * 2 * HID + HID + t], m2);
  }
  float* film = ws + FILM_OFF;
  film[((b * 4 + li) * 2 + 0) * HID + t] = 1.f + m1;
  film[((b * 4 + li) * 2 + 1) * HID + t] = m2;
}

// ---------------- prep_w: W -> fragment-linear hi/lo planes ----------------
__global__ __launch_bounds__(256) void prep_w(const float* __restrict__ Whg,
                                              float* __restrict__ ws) {
  const int li = blockIdx.x >> 3;
  const int c  = blockIdx.x & 7;
  const int t = threadIdx.x;
  const int lane = t & 63;
  const int n = lane & 15, q = lane >> 4;
  short* wp_hi = (short*)((char*)ws + WP_BYTE);
  short* wp_lo = wp_hi + PLANE_SHORTS;
  for (int h_t = (t >> 6); h_t < 16; h_t += 4) {
    short8 hv, lv;
    #pragma unroll
    for (int j = 0; j < 8; ++j) {
      float x = Whg[((size_t)(li * 256 + c * 32 + q * 8 + j)) * 256 + h_t * 16 + n];
      short hi, lo;
      split_trunc(x, hi, lo);
      hv[j] = hi; lv[j] = lo;
    }
    size_t off = ((((size_t)li * 16 + h_t) * 8 + c) * 64 + lane) * 8;
    *(short8*)&wp_hi[off] = hv;
    *(short8*)&wp_lo[off] = lv;
  }
}

// ---------------- FAST siren: term-pass MFMA ordering (16-deep dep distance) ----------------
__global__ __launch_bounds__(512) void siren_mfma_fast(
    const float* __restrict__ coords,
    const float* __restrict__ W0,
    const float* __restrict__ b0,
    const float* __restrict__ bhv,
    const float* __restrict__ Wl,
    const float* __restrict__ bl,
    const float* __restrict__ ws,
    float* __restrict__ out) {
  __shared__ short x_h[128 * 264];
  __shared__ short x_l[128 * 264];
  __shared__ float osum[128 * 4 * 3];
  const int tid = threadIdx.x;
  const int bp = blockIdx.x;
  const int b = bp >> 5;
  const int tile = bp & 31;
  const int pbase = b * NPTS + tile * PTILE;

  {
    const int quarter = tid >> 7;
    const int p = tid & 127;
    const float c0 = coords[(size_t)(pbase + p) * 2 + 0];
    const float c1 = coords[(size_t)(pbase + p) * 2 + 1];
    const int d0 = quarter * 64;
    for (int i = 0; i < 64; i += 8) {
      short8 hv, lv;
      #pragma unroll
      for (int j = 0; j < 8; ++j) {
        int d = d0 + i + j;
        float pre = fmaf(c0, W0[d], fmaf(c1, W0[HID + d], b0[d]));
        short hi, lo;
        split_trunc(__sinf(OMEGA_ * pre), hi, lo);
        hv[j] = hi; lv[j] = lo;
      }
      *(short8*)&x_h[p * 264 + d0 + i] = hv;
      *(short8*)&x_l[p * 264 + d0 + i] = lv;
    }
  }

  const int lane = tid & 63;
  const int wv = tid >> 6;
  const int pg = wv & 1;
  const int hq = wv >> 1;
  const int pb = pg * 64;
  const int hb = hq * 64;
  const int n = lane & 15;
  const int q = lane >> 4;

  const short* wp_hi = (const short*)((const char*)ws + WP_BYTE);
  const short* wp_lo = wp_hi + PLANE_SHORTS;
  const float* film = ws + FILM_OFF;

  for (int layer = 1; layer < NLAY; ++layer) {
    const int li = layer - 1;
    f32x4 acc[4][4];
    #pragma unroll
    for (int pt = 0; pt < 4; ++pt)
      #pragma unroll
      for (int ht = 0; ht < 4; ++ht)
        acc[pt][ht] = (f32x4){0.f, 0.f, 0.f, 0.f};

    __syncthreads();

    #pragma unroll 2
    for (int kc = 0; kc < HID; kc += 32) {
      const int c = kc >> 5;
      short8 Bh[4], Bl[4];
      #pragma unroll
      for (int ht = 0; ht < 4; ++ht) {
        const size_t wb = ((((size_t)li * 16 + hq * 4 + ht) * 8 + c) * 64 + lane) * 8;
        Bh[ht] = *(const short8*)&wp_hi[wb];
        Bl[ht] = *(const short8*)&wp_lo[wb];
      }
      short8 Ah[4], Al[4];
      #pragma unroll
      for (int pt = 0; pt < 4; ++pt) {
        const int xb = (pb + pt * 16 + n) * 264 + kc + q * 8;
        Ah[pt] = *(const short8*)&x_h[xb];
        Al[pt] = *(const short8*)&x_l[xb];
      }
      // term-pass ordering: each acc touched once per pass -> dependency
      // distance 16 MFMAs (was 1: three back-to-back on same acc = latency-bound)
      #pragma unroll
      for (int ht = 0; ht < 4; ++ht)
        #pragma unroll
        for (int pt = 0; pt < 4; ++pt)
          acc[pt][ht] = __builtin_amdgcn_mfma_f32_16x16x32_bf16(Ah[pt], Bh[ht], acc[pt][ht], 0, 0, 0);
      #pragma unroll
      for (int ht = 0; ht < 4; ++ht)
        #pragma unroll
        for (int pt = 0; pt < 4; ++pt)
          acc[pt][ht] = __builtin_amdgcn_mfma_f32_16x16x32_bf16(Ah[pt], Bl[ht], acc[pt][ht], 0, 0, 0);
      #pragma unroll
      for (int ht = 0; ht < 4; ++ht)
        #pragma unroll
        for (int pt = 0; pt < 4; ++pt)
          acc[pt][ht] = __builtin_amdgcn_mfma_f32_16x16x32_bf16(Al[pt], Bh[ht], acc[pt][ht], 0, 0, 0);
    }

    __syncthreads();

    #pragma unroll
    for (int ht = 0; ht < 4; ++ht) {
      const int h = hb + ht * 16 + n;
      const float bias = bhv[li * HID + h];
      const float g1 = film[((b * 4 + li) * 2 + 0) * HID + h];
      const float bt = film[((b * 4 + li) * 2 + 1) * HID + h];
      #pragma unroll
      for (int pt = 0; pt < 4; ++pt) {
        #pragma unroll
        for (int r = 0; r < 4; ++r) {
          float pre = acc[pt][ht][r] + bias;
          pre = fmaf(pre, g1, bt);
          short hi, lo;
          split_trunc(__sinf(OMEGA_ * pre), hi, lo);
          const int row = pb + pt * 16 + q * 4 + r;
          x_h[row * 264 + h] = hi;
          x_l[row * 264 + h] = lo;
        }
      }
    }
  }
  __syncthreads();

  {
    const int p = tid >> 2;
    const int dq = tid & 3;
    float v0 = 0.f, v1 = 0.f, v2 = 0.f;
    for (int i = 0; i < 64; ++i) {
      int d = dq * 64 + i;
      float xv = bf16_hi_f((unsigned short)x_h[p * 264 + d]) +
                 bf16_hi_f((unsigned short)x_l[p * 264 + d]);
      v0 = fmaf(xv, Wl[d * 3 + 0], v0);
      v1 = fmaf(xv, Wl[d * 3 + 1], v1);
      v2 = fmaf(xv, Wl[d * 3 + 2], v2);
    }
    osum[(p * 4 + dq) * 3 + 0] = v0;
    osum[(p * 4 + dq) * 3 + 1] = v1;
    osum[(p * 4 + dq) * 3 + 2] = v2;
  }
  __syncthreads();
  if (tid < PTILE) {
    const int p = tid;
    float v[3] = {bl[0], bl[1], bl[2]};
    #pragma unroll
    for (int dq = 0; dq < 4; ++dq)
      #pragma unroll
      for (int c = 0; c < 3; ++c) v[c] += osum[(p * 4 + dq) * 3 + c];
    size_t o = (size_t)(pbase + p) * 3;
    out[o + 0] = v[0]; out[o + 1] = v[1]; out[o + 2] = v[2];
  }
}

// ---------------- FALLBACK siren (round-8-proven; dead code when ws large) ----------------
__global__ __launch_bounds__(512) void siren_mfma(
    const float* __restrict__ coords,
    const float* __restrict__ W0,
    const float* __restrict__ b0,
    const float* __restrict__ Whg,
    const float* __restrict__ bhv,
    const float* __restrict__ Wl,
    const float* __restrict__ bl,
    const float* __restrict__ ws,
    float* __restrict__ out) {
  __shared__ unsigned int x_u[128 * 260];
  __shared__ float osum[128 * 4 * 3];
  const int tid = threadIdx.x;
  const int bp = blockIdx.x;
  const int b = bp >> 5;
  const int tile = bp & 31;
  const int pbase = b * NPTS + tile * PTILE;
  {
    const int quarter = tid >> 7;
    const int p = tid & 127;
    const float c0 = coords[(size_t)(pbase + p) * 2 + 0];
    const float c1 = coords[(size_t)(pbase + p) * 2 + 1];
    const int d0 = quarter * 64;
    for (int i = 0; i < 64; i += 4) {
      unsigned int buf[4];
      #pragma unroll
      for (int j = 0; j < 4; ++j) {
        int d = d0 + i + j;
        float pre = fmaf(c0, W0[d], fmaf(c1, W0[HID + d], b0[d]));
        buf[j] = pack_split(__sinf(OMEGA_ * pre));
      }
      *(uint4*)&x_u[p * 260 + d0 + i] = *(uint4*)buf;
    }
  }
  const int lane = tid & 63;
  const int wv = tid >> 6;
  const int pg = wv & 1;
  const int hq = wv >> 1;
  const int pb = pg * 64;
  const int hb = hq * 64;
  const int n = lane & 15;
  const int q = lane >> 4;
  const float* film = ws + FILM_OFF;
  for (int layer = 1; layer < NLAY; ++layer) {
    const int li = layer - 1;
    f32x4 acc[4][4];
    #pragma unroll
    for (int pt = 0; pt < 4; ++pt)
      #pragma unroll
      for (int ht = 0; ht < 4; ++ht)
        acc[pt][ht] = (f32x4){0.f, 0.f, 0.f, 0.f};
    __syncthreads();
    for (int kc = 0; kc < HID; kc += 32) {
      short8 Bh[4], Bl[4];
      #pragma unroll
      for (int ht = 0; ht < 4; ++ht) {
        const float* wbase = Whg + ((size_t)(li * 256 + kc + q * 8)) * 256 + hb + ht * 16 + n;
        #pragma unroll
        for (int j = 0; j < 8; ++j) {
          short hi, lo;
          split_trunc(wbase[(size_t)j * 256], hi, lo);
          Bh[ht][j] = hi; Bl[ht][j] = lo;
        }
      }
      short8 ah[4], al[4];
      #pragma unroll
      for (int pt = 0; pt < 4; ++pt) {
        const uint4* ap = (const uint4*)&x_u[(pb + pt * 16 + n) * 260 + kc + q * 8];
        uint4 a0 = ap[0], a1 = ap[1];
        unsigned int aw[8] = {a0.x, a0.y, a0.z, a0.w, a1.x, a1.y, a1.z, a1.w};
        #pragma unroll
        for (int j = 0; j < 8; ++j) {
          ah[pt][j] = (short)(aw[j] >> 16);
          al[pt][j] = (short)(aw[j] & 0xffffu);
        }
      }
      #pragma unroll
      for (int ht = 0; ht < 4; ++ht)
        #pragma unroll
        for (int pt = 0; pt < 4; ++pt)
          acc[pt][ht] = __builtin_amdgcn_mfma_f32_16x16x32_bf16(ah[pt], Bh[ht], acc[pt][ht], 0, 0, 0);
      #pragma unroll
      for (int ht = 0; ht < 4; ++ht)
        #pragma unroll
        for (int pt = 0; pt < 4; ++pt)
          acc[pt][ht] = __builtin_amdgcn_mfma_f32_16x16x32_bf16(ah[pt], Bl[ht], acc[pt][ht], 0, 0, 0);
      #pragma unroll
      for (int ht = 0; ht < 4; ++ht)
        #pragma unroll
        for (int pt = 0; pt < 4; ++pt)
          acc[pt][ht] = __builtin_amdgcn_mfma_f32_16x16x32_bf16(al[pt], Bh[ht], acc[pt][ht], 0, 0, 0);
    }
    __syncthreads();
    #pragma unroll
    for (int ht = 0; ht < 4; ++ht) {
      const int h = hb + ht * 16 + n;
      const float bias = bhv[li * HID + h];
      const float g1 = film[((b * 4 + li) * 2 + 0) * HID + h];
      const float bt = film[((b * 4 + li) * 2 + 1) * HID + h];
      #pragma unroll
      for (int pt = 0; pt < 4; ++pt) {
        #pragma unroll
        for (int r = 0; r < 4; ++r) {
          float pre = acc[pt][ht][r] + bias;
          pre = fmaf(pre, g1, bt);
          x_u[(pb + pt * 16 + q * 4 + r) * 260 + h] = pack_split(__sinf(OMEGA_ * pre));
        }
      }
    }
  }
  __syncthreads();
  {
    const int p = tid >> 2;
    const int dq = tid & 3;
    float v0 = 0.f, v1 = 0.f, v2 = 0.f;
    for (int i = 0; i < 64; ++i) {
      int d = dq * 64 + i;
      unsigned int wrd = x_u[p * 260 + d];
      float xv = bf16_hi_f((unsigned short)(wrd >> 16)) +
                 bf16_hi_f((unsigned short)(wrd & 0xffffu));
      v0 = fmaf(xv, Wl[d * 3 + 0], v0);
      v1 = fmaf(xv, Wl[d * 3 + 1], v1);
      v2 = fmaf(xv, Wl[d * 3 + 2], v2);
    }
    osum[(p * 4 + dq) * 3 + 0] = v0;
    osum[(p * 4 + dq) * 3 + 1] = v1;
    osum[(p * 4 + dq) * 3 + 2] = v2;
  }
  __syncthreads();
  if (tid < PTILE) {
    const int p = tid;
    float v[3] = {bl[0], bl[1], bl[2]};
    #pragma unroll
    for (int dq = 0; dq < 4; ++dq)
      #pragma unroll
      for (int c = 0; c < 3; ++c) v[c] += osum[(p * 4 + dq) * 3 + c];
    size_t o = (size_t)(pbase + p) * 3;
    out[o + 0] = v[0]; out[o + 1] = v[1]; out[o + 2] = v[2];
  }
}

extern "C" void kernel_launch(void* const* d_in, const int* in_sizes, int n_in,
                              void* d_out, int out_size, void* d_ws, size_t ws_size,
                              hipStream_t stream) {
  (void)in_sizes; (void)n_in;
  const float* coords  = (const float*)d_in[0];
  const int*   lidx    = (const int*)d_in[1];
  const float* latents = (const float*)d_in[2];
  const float* emb     = (const float*)d_in[3];
  const float* mod_W   = (const float*)d_in[4];
  const float* mod_b   = (const float*)d_in[5];
  const float* W0      = (const float*)d_in[6];
  const float* b0      = (const float*)d_in[7];
  const float* Wh      = (const float*)d_in[8];
  const float* bh      = (const float*)d_in[9];
  const float* Wl      = (const float*)d_in[10];
  const float* bl      = (const float*)d_in[11];
  float* out = (float*)d_out;
  float* ws  = (float*)d_ws;
  float* loss_out = out + (out_size - 1);

  const bool fast = (ws_size >= FAST_WS_NEEDED);
  if (fast) prep_w<<<32, 256, 0, stream>>>(Wh, ws);
  vq_init<<<BATCH, 256, 0, stream>>>(lidx, latents, ws);
  for (int s = 0; s < NVQ; ++s)
    vq_stage<<<BATCH * 8, 256, 0, stream>>>(emb, ws, s);
  film_loss<<<BATCH * 4 + 1, 256, 0, stream>>>(emb, mod_W, mod_b, ws, loss_out);
  if (fast)
    siren_mfma_fast<<<(BATCH * NPTS) / PTILE, 512, 0, stream>>>(coords, W0, b0, bh, Wl, bl, ws, out);
  else
    siren_mfma<<<(BATCH * NPTS) / PTILE, 512, 0, stream>>>(coords, W0, b0, Wh, bh, Wl, bl, ws, out);
}